// Round 10
// baseline (97.126 us; speedup 1.0000x reference)
//
#include <hip/hip_runtime.h>
#include <math.h>

// dist[b,n] = sum_d softplus(fw[d]) * |q[b,d] - X[n,d]|
//
// Round 10: q via HOT scalar path, X in VGPRs, w in VGPRs.
//   inner:  v_sub_f32 vt, s_q, v_x          (1 SGPR operand - legal)
//           v_fma_f32 a, v_w, abs(vt), a    (VOP3 + abs modifier)
//   = 2 VALU/elem, exact reference math, no pre-scaling, no prep kernel.
// q (16 KB) is re-read by every block -> sL1/L2-resident scalar loads
// (round 9 failed because X streamed COLD through the scalar pipe at 1.6
// waves/SIMD; here q is hot and b-tiling supplies 3 waves/SIMD).
// Round 4's failure cause now removed: unroll 1 keeps ONE 64-SGPR q row
// live (r4's unroll 2 blew the ~102 SGPR budget -> demotion), and w-in-
// VGPR removes the serial prep kernel.

constexpr int D = 64;
constexpr int BCHUNK = 16;   // b per block -> 4 chunks, X read 4x (L2/L3-hot)
constexpr int NT = 256;      // 4 waves
constexpr int ROWS = 256;    // 1 X row per thread
constexpr int PADF = 68;     // staging LDS row stride (floats)

__global__ __launch_bounds__(NT, 3)
void fdist_kernel(const float* __restrict__ q,
                  const float* __restrict__ X,
                  const float* __restrict__ fw,
                  float* __restrict__ out, int N) {
    __shared__ float xbuf[4][32 * PADF];   // per-wave staging, 34.8 KB total

    const int t = threadIdx.x;
    const int w = t >> 6, l = t & 63;

    // XCD swizzle (nwg % 8 == 0): consecutive wg on one XCD = 4 b-chunks of
    // the SAME X slice -> X re-reads are XCD-local L2 hits.
    const int nwg = gridDim.x, cpx = nwg >> 3;
    const int wg = (blockIdx.x & 7) * cpx + (blockIdx.x >> 3);
    const int nbase = (wg >> 2) * ROWS;
    const int bbase = (wg & 3) * BCHUNK;

    // ---- softplus(fw) into 64 VGPRs (once per thread, ~negligible) ----
    const float4* fw4 = reinterpret_cast<const float4*>(fw);
    float4 wv[16];
#pragma unroll
    for (int c = 0; c < 16; ++c) {
        const float4 f = fw4[c];
        wv[c].x = fmaxf(f.x, 0.f) + log1pf(expf(-fabsf(f.x)));
        wv[c].y = fmaxf(f.y, 0.f) + log1pf(expf(-fabsf(f.y)));
        wv[c].z = fmaxf(f.z, 0.f) + log1pf(expf(-fabsf(f.z)));
        wv[c].w = fmaxf(f.w, 0.f) + log1pf(expf(-fabsf(f.w)));
    }

    // ---- X row into 64 VGPRs via per-wave barrier-free LDS transpose ----
    const int col = l & 15, rsub = l >> 4;
    float* wb = xbuf[w];
    const float4* Xv = reinterpret_cast<const float4*>(X);
    float4 xs[16];
#pragma unroll
    for (int p = 0; p < 2; ++p) {
#pragma unroll
        for (int j = 0; j < 8; ++j) {
            const int r = j * 4 + rsub;                   // 0..31
            int grow = nbase + w * 64 + p * 32 + r;
            grow = grow < N ? grow : N - 1;
            const float4 v = Xv[(size_t)grow * 16 + col]; // coalesced 1KB/instr
            *reinterpret_cast<float4*>(&wb[r * PADF + col * 4]) = v;
        }
        asm volatile("s_waitcnt vmcnt(0) lgkmcnt(0)" ::: "memory");
        if ((l >> 5) == p) {
#pragma unroll
            for (int i = 0; i < 16; ++i)
                xs[i] = *reinterpret_cast<const float4*>(&wb[(l & 31) * PADF + i * 4]);
        }
        asm volatile("s_waitcnt lgkmcnt(0)" ::: "memory");
    }

    const int n = nbase + t;
    const bool valid = n < N;
    const float4* q4 = reinterpret_cast<const float4*>(q);

    // ---- main loop: q row via wave-uniform (scalar) loads, unroll 1 so
    //      exactly ONE 64-SGPR row is live; w and X from VGPRs ----
#pragma unroll 1
    for (int bi = 0; bi < BCHUNK; ++bi) {
        const float4* __restrict__ qrow = q4 + (size_t)(bbase + bi) * 16;
        float a0 = 0.f, a1 = 0.f, a2 = 0.f, a3 = 0.f;
#pragma unroll
        for (int c = 0; c < 16; ++c) {
            const float4 qv = qrow[c];                   // uniform -> s_load
            a0 = fmaf(wv[c].x, fabsf(qv.x - xs[c].x), a0);
            a1 = fmaf(wv[c].y, fabsf(qv.y - xs[c].y), a1);
            a2 = fmaf(wv[c].z, fabsf(qv.z - xs[c].z), a2);
            a3 = fmaf(wv[c].w, fabsf(qv.w - xs[c].w), a3);
        }
        if (valid) out[(size_t)(bbase + bi) * N + n] = (a0 + a1) + (a2 + a3);
    }
}

extern "C" void kernel_launch(void* const* d_in, const int* in_sizes, int n_in,
                              void* d_out, int out_size, void* d_ws, size_t ws_size,
                              hipStream_t stream) {
    const float* q  = (const float*)d_in[0];
    const float* X  = (const float*)d_in[1];
    const float* fw = (const float*)d_in[2];
    float* out = (float*)d_out;

    const int B = in_sizes[0] / D;  // 64
    const int N = in_sizes[1] / D;  // 50000

    const int nxblk = (N + ROWS - 1) / ROWS;      // 196
    const int nwg = nxblk * (B / BCHUNK);         // 784 (divisible by 8)
    fdist_kernel<<<dim3(nwg), dim3(NT), 0, stream>>>(q, X, fw, out, N);
}